// Round 5
// baseline (183.669 us; speedup 1.0000x reference)
//
#include <hip/hip_runtime.h>
#include <stdint.h>
#include <stddef.h>

#define S_LEN 2048
#define NH 16
#define HD 64          // head dim
#define DM 1024        // model dim
#define NQKV 3072      // 3*DM
#define MROWS 4096     // B*S
#define NBH 32         // B*NH

typedef float f32x4 __attribute__((ext_vector_type(4)));
typedef float f32x16 __attribute__((ext_vector_type(16)));
typedef __bf16 bf16x8 __attribute__((ext_vector_type(8)));
typedef __bf16 bf16x2v __attribute__((ext_vector_type(2)));
typedef short short8_t __attribute__((ext_vector_type(8)));
typedef unsigned int u32x4 __attribute__((ext_vector_type(4)));

// round-to-nearest-even fp32 -> bf16 (inputs finite)
__device__ __forceinline__ unsigned short f2bf(float f) {
  union { float f; unsigned int u; } v; v.f = f;
  unsigned int u = v.u;
  u += 0x7FFFu + ((u >> 16) & 1u);
  return (unsigned short)(u >> 16);
}

// async global->LDS, 16B per lane. LDS dest must be (wave-uniform base + lane*16).
__device__ __forceinline__ void async_copy16(const void* g, void* l) {
  __builtin_amdgcn_global_load_lds(
      (const __attribute__((address_space(1))) void*)g,
      (__attribute__((address_space(3))) void*)l, 16, 0, 0);
}

// ---------------- precast x -> bf16 ----------------
__global__ __launch_bounds__(256) void cast_x_kernel(const float* __restrict__ x,
                                                     unsigned short* __restrict__ xb) {
  size_t i = ((size_t)blockIdx.x * 256 + threadIdx.x) * 8;
  f32x4 a = *(const f32x4*)(x + i);
  f32x4 b = *(const f32x4*)(x + i + 4);
  union { unsigned short u[8]; short8_t v; } o;
  o.u[0] = f2bf(a[0]); o.u[1] = f2bf(a[1]); o.u[2] = f2bf(a[2]); o.u[3] = f2bf(a[3]);
  o.u[4] = f2bf(b[0]); o.u[5] = f2bf(b[1]); o.u[6] = f2bf(b[2]); o.u[7] = f2bf(b[3]);
  *(short8_t*)(xb + i) = o.v;
}

// ---------------- W[K][N] -> Wt[N][K] bf16 (LDS tile transpose) ----------------
__global__ __launch_bounds__(256) void transpose_w_kernel(const float* __restrict__ W,
                                                          unsigned short* __restrict__ wt) {
  __shared__ float tile[32][33];
  const int n0 = blockIdx.x * 32;
  const int k0 = blockIdx.y * 32;
  const int tx = threadIdx.x;   // 0..31
  const int ty = threadIdx.y;   // 0..7
  #pragma unroll
  for (int i = 0; i < 4; ++i)
    tile[ty + i * 8][tx] = W[(size_t)(k0 + ty + i * 8) * NQKV + n0 + tx];
  __syncthreads();
  #pragma unroll
  for (int i = 0; i < 4; ++i)
    wt[(size_t)(n0 + ty + i * 8) * DM + k0 + tx] = f2bf(tile[tx][ty + i * 8]);
}

// ---------------- QKV GEMM: [4096,1024] x [1024,3072] + bias -> Q,K,V^T (bf16) ----------------
__global__ __launch_bounds__(256) void qkv_gemm_kernel(
    const unsigned short* __restrict__ xb, const unsigned short* __restrict__ wt,
    const float* __restrict__ bias,
    unsigned short* __restrict__ Qb, unsigned short* __restrict__ Kb,
    unsigned short* __restrict__ Vt) {
  __shared__ __align__(16) unsigned char As[128 * 128];  // 128 rows x 64 bf16
  __shared__ __align__(16) unsigned char Bs[128 * 128];
  const int t = threadIdx.x;
  const int lane = t & 63;
  const int wave = t >> 6;
  const int wm = (wave >> 1) * 64, wn = (wave & 1) * 64;
  const int lr = lane & 15, g = lane >> 4;
  const int m0 = blockIdx.x * 128, n0 = blockIdx.y * 128;

  f32x4 acc[4][4];
  #pragma unroll
  for (int i = 0; i < 4; ++i)
    #pragma unroll
    for (int j = 0; j < 4; ++j) acc[i][j] = f32x4{0.f, 0.f, 0.f, 0.f};

  for (int k0 = 0; k0 < DM; k0 += 64) {
    __syncthreads();
    #pragma unroll
    for (int i = 0; i < 4; ++i) {
      int c = t + i * 256;            // 1024 chunks of 16B per tile
      int row = c >> 3;               // 0..127
      int cc = (c & 7) ^ (row & 7);   // inverse swizzle on the GLOBAL side
      async_copy16(xb + (size_t)(m0 + row) * DM + k0 + cc * 8, As + c * 16);
      async_copy16(wt + (size_t)(n0 + row) * DM + k0 + cc * 8, Bs + c * 16);
    }
    __syncthreads();  // barrier drains vmcnt -> tiles ready

    bf16x8 af[2][4], bfr[2][4];
    #pragma unroll
    for (int kk = 0; kk < 2; ++kk) {
      #pragma unroll
      for (int i = 0; i < 4; ++i) {
        int ra = wm + i * 16 + lr;
        af[kk][i] = *(const bf16x8*)(As + ((ra * 128 + kk * 64 + g * 16) ^ ((ra & 7) << 4)));
        int rb = wn + i * 16 + lr;
        bfr[kk][i] = *(const bf16x8*)(Bs + ((rb * 128 + kk * 64 + g * 16) ^ ((rb & 7) << 4)));
      }
    }
    #pragma unroll
    for (int kk = 0; kk < 2; ++kk)
      #pragma unroll
      for (int mi = 0; mi < 4; ++mi)
        #pragma unroll
        for (int ni = 0; ni < 4; ++ni)
          acc[mi][ni] = __builtin_amdgcn_mfma_f32_16x16x32_bf16(
              af[kk][mi], bfr[kk][ni], acc[mi][ni], 0, 0, 0);
  }

  // epilogue: +bias, route column n -> (head, q/k/v, d); V stored transposed [bh][d][s]
  const float QSC = 0.18033688011112042f;  // 1/sqrt(64) * log2(e), folded into Q
  #pragma unroll
  for (int ni = 0; ni < 4; ++ni) {
    int n = n0 + wn + ni * 16 + lr;
    float bv = bias[n];
    int h = n / 192;
    int rr = n % 192;
    int typ = rr >> 6;
    int d = rr & 63;
    #pragma unroll
    for (int mi = 0; mi < 4; ++mi) {
      #pragma unroll
      for (int r = 0; r < 4; ++r) {
        int m = m0 + wm + mi * 16 + g * 4 + r;   // C row = (lane>>4)*4+reg (verified layout)
        int b = m >> 11, s = m & 2047;
        int bh = b * NH + h;
        float v = acc[mi][ni][r] + bv;
        if (typ == 0)      Qb[((size_t)bh * S_LEN + s) * HD + d] = f2bf(v * QSC);
        else if (typ == 1) Kb[((size_t)bh * S_LEN + s) * HD + d] = f2bf(v);
        else               Vt[((size_t)bh * HD + d) * S_LEN + s] = f2bf(v);
      }
    }
  }
}

// ---------------- flash attention: 32x32 MFMA, split-K waves, in-register P ----------------
// Block = 4 waves (wq: q-half, wk: key-half). 64 q-rows/block, KVBLK=64 staged dbuf.
// Wave computes 32 q x 32 keys per tile: S^T = mfma32(K, Q) seeded with -m; lane
// (l5,hi) holds 16 S values of row q=l5. P converted to bf16 in-register and
// redistributed to the PV B-fragment with 4 v_permlane32_swap_b32 (no LDS!).
// O^T = mfma32(V^T, P^T). wk halves merge (m,l,O) through LDS at the end.
__global__ __launch_bounds__(256, 4) void attn_kernel(
    const unsigned short* __restrict__ Qb, const unsigned short* __restrict__ Kb,
    const unsigned short* __restrict__ Vt, float* __restrict__ out) {
  __shared__ __align__(16) unsigned char Ks[2][64 * 128];   // K tile [64 keys][64 d]
  __shared__ __align__(16) unsigned char Vs[2][64 * 128];   // V^T tile [64 d][64 keys]
  const int t = threadIdx.x;
  const int lane = t & 63;
  const int wave = t >> 6;
  const int l5 = lane & 31, hi = lane >> 5;
  const int wq = wave >> 1, wk = wave & 1;

  // XCD-aware swizzle: 1024 blocks, wg%8 = XCD -> each XCD owns 4 whole bh
  const int wg = blockIdx.x;
  const int bh = (wg & 7) * 4 + ((wg >> 3) & 3);
  const int q0 = (wg >> 5) * 64 + wq * 32;

  const unsigned short* Kbh = Kb + (size_t)bh * S_LEN * HD;
  const unsigned short* Vbh = Vt + (size_t)bh * HD * S_LEN;

  // Q fragment (pre-scaled by 1/8*log2e): B-frag, lane (l5,hi): k = kk*16+8hi+j
  const unsigned short* Qrow = Qb + ((size_t)bh * S_LEN + q0 + l5) * HD;
  bf16x8 qf[4];
  #pragma unroll
  for (int kk = 0; kk < 4; ++kk)
    qf[kk] = *(const bf16x8*)(Qrow + kk * 16 + hi * 8);

  // loop-invariant swizzled LDS offsets
  int kOff[4];                      // K rows = wk*32 + l5, all 4 k-steps
  {
    int row = wk * 32 + l5;
    #pragma unroll
    for (int kk = 0; kk < 4; ++kk)
      kOff[kk] = (row * 128 + kk * 32 + hi * 16) ^ ((row & 7) << 4);
  }
  int vOff[2][2];                   // V^T rows d = ds*32 + l5, cols = my key half
  #pragma unroll
  for (int ds = 0; ds < 2; ++ds)
    #pragma unroll
    for (int kkl = 0; kkl < 2; ++kkl) {
      int rv = ds * 32 + l5;
      vOff[ds][kkl] = (rv * 128 + (2 * wk + kkl) * 32 + hi * 16) ^ ((rv & 7) << 4);
    }

  // staging: per-lane source offsets (elements) and LDS chunk indices
  const int c0 = t, c1 = t + 256;
  const int row0 = c0 >> 3, row1 = c1 >> 3;
  const int cc0 = (c0 & 7) ^ (row0 & 7), cc1 = (c1 & 7) ^ (row1 & 7);
  const int kGO0 = row0 * HD + cc0 * 8, kGO1 = row1 * HD + cc1 * 8;
  const int vGO0 = row0 * S_LEN + cc0 * 8, vGO1 = row1 * S_LEN + cc1 * 8;

  float m = 0.f, lsum = 0.f;        // per-q (redundant across the hi lane pair)
  f32x16 oacc[2];
  #pragma unroll
  for (int ds = 0; ds < 2; ++ds)
    #pragma unroll
    for (int i = 0; i < 16; ++i) oacc[ds][i] = 0.f;

  auto stage = [&](int kt, int buf) __attribute__((always_inline)) {
    const unsigned short* kp = Kbh + (size_t)kt * (64 * HD);
    const unsigned short* vp = Vbh + kt * 64;
    async_copy16(kp + kGO0, &Ks[buf][c0 * 16]);
    async_copy16(vp + vGO0, &Vs[buf][c0 * 16]);
    async_copy16(kp + kGO1, &Ks[buf][c1 * 16]);
    async_copy16(vp + vGO1, &Vs[buf][c1 * 16]);
  };

  auto compute = [&](int buf) __attribute__((always_inline)) {
    // S^T - m for my 32-key half (keys 32*wk + (r&3)+8*(r>>2)+4*hi, q = l5)
    const float nm = -m;
    f32x16 sacc;
    #pragma unroll
    for (int i = 0; i < 16; ++i) sacc[i] = nm;
    __builtin_amdgcn_s_setprio(1);
    #pragma unroll
    for (int kk = 0; kk < 4; ++kk) {
      bf16x8 kf = *(const bf16x8*)(&Ks[buf][kOff[kk]]);
      sacc = __builtin_amdgcn_mfma_f32_32x32x16_bf16(kf, qf[kk], sacc, 0, 0, 0);
    }
    __builtin_amdgcn_s_setprio(0);

    // lane-local max of 16 values (compiler fuses to v_max3)
    float tm = fmaxf(sacc[0], sacc[1]);
    #pragma unroll
    for (int i = 2; i < 16; ++i) tm = fmaxf(tm, sacc[i]);

    if (!__all(tm <= 8.f)) {         // rare: real max growth -> exact rescale
      float tmr = fmaxf(tm, __shfl_xor(tm, 32));
      float alpha = exp2f(-tmr);
      m += tmr;
      lsum *= alpha;
      oacc[0] *= alpha;
      oacc[1] *= alpha;
      sacc -= tmr;
    }

    // P = exp2(S-m) <= 2^8; row-sum in f32; pack to bf16 pairs in-register
    float s = 0.f;
    unsigned wv[8];
    #pragma unroll
    for (int rr = 0; rr < 8; ++rr) {
      float p0 = exp2f(sacc[2 * rr]);
      float p1 = exp2f(sacc[2 * rr + 1]);
      s += p0 + p1;
      bf16x2v c; c[0] = (__bf16)p0; c[1] = (__bf16)p1;
      wv[rr] = __builtin_bit_cast(unsigned, c);
    }
    s += __shfl_xor(s, 32);          // pair (l5, l5+32) covers my full 32-key half
    lsum += s;

    // P^T B-fragment via permlane32_swap: pf[kkl] holds keys 16*kkl+8*hi+{0..7}
    bf16x8 pf[2];
    #pragma unroll
    for (int kkl = 0; kkl < 2; ++kkl) {
      unsigned a0 = wv[4 * kkl + 0], b0 = wv[4 * kkl + 2];
      asm("v_permlane32_swap_b32 %0, %1" : "+v"(a0), "+v"(b0));
      unsigned a1 = wv[4 * kkl + 1], b1 = wv[4 * kkl + 3];
      asm("v_permlane32_swap_b32 %0, %1" : "+v"(a1), "+v"(b1));
      u32x4 tmp; tmp[0] = a0; tmp[1] = a1; tmp[2] = b0; tmp[3] = b1;
      pf[kkl] = __builtin_bit_cast(bf16x8, tmp);
    }

    // O^T += V^T . P^T  (my key half only)
    __builtin_amdgcn_s_setprio(1);
    #pragma unroll
    for (int ds = 0; ds < 2; ++ds)
      #pragma unroll
      for (int kkl = 0; kkl < 2; ++kkl) {
        bf16x8 vf = *(const bf16x8*)(&Vs[buf][vOff[ds][kkl]]);
        oacc[ds] = __builtin_amdgcn_mfma_f32_32x32x16_bf16(vf, pf[kkl], oacc[ds], 0, 0, 0);
      }
    __builtin_amdgcn_s_setprio(0);
  };

  stage(0, 0);
  __syncthreads();  // drains vmcnt -> tile 0 ready

  for (int kt = 0; kt < S_LEN / 64; kt += 2) {
    stage(kt + 1, 1);                // prefetch overlaps compute
    compute(0);
    __syncthreads();                 // buf1 landed; buf0 reads done
    if (kt + 2 < S_LEN / 64) stage(kt + 2, 0);
    compute(1);
    __syncthreads();                 // buf0 landed; buf1 reads done
  }

  // ---- merge wk=0 / wk=1 partials through LDS (K/V buffers are dead now) ----
  float* obuf = (float*)&Ks[0][0];   // 2 wq x 64 lanes x 32 f32 = 16 KB (all of Ks)
  float* mlbuf = (float*)&Vs[0][0];  // m: [0..63], l: [64..127]
  if (wk == 1) {
    float* dst = obuf + (wq * 64 + lane) * 32;
    #pragma unroll
    for (int ds = 0; ds < 2; ++ds)
      #pragma unroll
      for (int i = 0; i < 4; ++i) {
        f32x4 v;
        #pragma unroll
        for (int j = 0; j < 4; ++j) v[j] = oacc[ds][i * 4 + j];
        *(f32x4*)(dst + ds * 16 + i * 4) = v;
      }
    if (hi == 0) { mlbuf[wq * 32 + l5] = m; mlbuf[64 + wq * 32 + l5] = lsum; }
  }
  __syncthreads();
  if (wk == 0) {
    float m1 = mlbuf[wq * 32 + l5];
    float l1 = mlbuf[64 + wq * 32 + l5];
    float mF = fmaxf(m, m1);
    float a0 = exp2f(m - mF), a1 = exp2f(m1 - mF);
    float inv = 1.0f / (lsum * a0 + l1 * a1);
    const float* src = obuf + (wq * 64 + lane) * 32;
    float* outp = out + ((size_t)bh * S_LEN + q0 + l5) * HD;
    #pragma unroll
    for (int ds = 0; ds < 2; ++ds)
      #pragma unroll
      for (int i = 0; i < 4; ++i) {
        f32x4 v;
        #pragma unroll
        for (int j = 0; j < 4; ++j)
          v[j] = (oacc[ds][i * 4 + j] * a0 + src[ds * 16 + i * 4 + j] * a1) * inv;
        // d = ds*32 + 8*i + 4*hi + j
        *(f32x4*)(outp + ds * 32 + i * 8 + hi * 4) = v;
      }
  }
}

extern "C" void kernel_launch(void* const* d_in, const int* in_sizes, int n_in,
                              void* d_out, int out_size, void* d_ws, size_t ws_size,
                              hipStream_t stream) {
  const float* x    = (const float*)d_in[0];
  const float* W    = (const float*)d_in[1];
  const float* bias = (const float*)d_in[2];
  float* out = (float*)d_out;

  // workspace partition (bf16 everywhere): ~38 MB total
  unsigned short* xb = (unsigned short*)d_ws;
  unsigned short* wt = xb + (size_t)MROWS * DM;
  unsigned short* Qb = wt + (size_t)NQKV * DM;
  unsigned short* Kb = Qb + (size_t)NBH * S_LEN * HD;
  unsigned short* Vt = Kb + (size_t)NBH * S_LEN * HD;

  cast_x_kernel<<<(MROWS * DM) / (256 * 8), 256, 0, stream>>>(x, xb);
  transpose_w_kernel<<<dim3(NQKV / 32, DM / 32), dim3(32, 8), 0, stream>>>(W, wt);
  qkv_gemm_kernel<<<dim3(MROWS / 128, NQKV / 128), 256, 0, stream>>>(xb, wt, bias, Qb, Kb, Vt);
  attn_kernel<<<NBH * (S_LEN / 64), 256, 0, stream>>>(Qb, Kb, Vt, out);
}

// Round 6
// 129.354 us; speedup vs baseline: 1.4199x; 1.4199x over previous
//
#include <hip/hip_runtime.h>
#include <stdint.h>
#include <stddef.h>

#define S_LEN 2048
#define NH 16
#define HD 64          // head dim
#define DM 1024        // model dim
#define NQKV 3072      // 3*DM
#define MROWS 4096     // B*S
#define NBH 32         // B*NH

typedef float f32x4 __attribute__((ext_vector_type(4)));
typedef __bf16 bf16x8 __attribute__((ext_vector_type(8)));
typedef __bf16 bf16x4 __attribute__((ext_vector_type(4)));
typedef short short8_t __attribute__((ext_vector_type(8)));

// round-to-nearest-even fp32 -> bf16 (inputs finite)
__device__ __forceinline__ unsigned short f2bf(float f) {
  union { float f; unsigned int u; } v; v.f = f;
  unsigned int u = v.u;
  u += 0x7FFFu + ((u >> 16) & 1u);
  return (unsigned short)(u >> 16);
}

// async global->LDS, 16B per lane. LDS dest must be (wave-uniform base + lane*16).
__device__ __forceinline__ void async_copy16(const void* g, void* l) {
  __builtin_amdgcn_global_load_lds(
      (const __attribute__((address_space(1))) void*)g,
      (__attribute__((address_space(3))) void*)l, 16, 0, 0);
}

// ---------------- precast x -> bf16 ----------------
__global__ __launch_bounds__(256) void cast_x_kernel(const float* __restrict__ x,
                                                     unsigned short* __restrict__ xb) {
  size_t i = ((size_t)blockIdx.x * 256 + threadIdx.x) * 8;
  f32x4 a = *(const f32x4*)(x + i);
  f32x4 b = *(const f32x4*)(x + i + 4);
  union { unsigned short u[8]; short8_t v; } o;
  o.u[0] = f2bf(a[0]); o.u[1] = f2bf(a[1]); o.u[2] = f2bf(a[2]); o.u[3] = f2bf(a[3]);
  o.u[4] = f2bf(b[0]); o.u[5] = f2bf(b[1]); o.u[6] = f2bf(b[2]); o.u[7] = f2bf(b[3]);
  *(short8_t*)(xb + i) = o.v;
}

// ---------------- W[K][N] -> Wt[N][K] bf16 (LDS tile transpose) ----------------
__global__ __launch_bounds__(256) void transpose_w_kernel(const float* __restrict__ W,
                                                          unsigned short* __restrict__ wt) {
  __shared__ float tile[32][33];
  const int n0 = blockIdx.x * 32;
  const int k0 = blockIdx.y * 32;
  const int tx = threadIdx.x;   // 0..31
  const int ty = threadIdx.y;   // 0..7
  #pragma unroll
  for (int i = 0; i < 4; ++i)
    tile[ty + i * 8][tx] = W[(size_t)(k0 + ty + i * 8) * NQKV + n0 + tx];
  __syncthreads();
  #pragma unroll
  for (int i = 0; i < 4; ++i)
    wt[(size_t)(n0 + ty + i * 8) * DM + k0 + tx] = f2bf(tile[tx][ty + i * 8]);
}

// ---------------- QKV GEMM: [4096,1024] x [1024,3072] + bias -> Q,K,V^T (bf16) ----------------
// 128x128 tile, BK=64, 4 waves (2x2), 16x16x32 bf16 MFMA, global_load_lds staging
// with pre-swizzled source so LDS reads (^((row&7)<<4)) are bank-conflict-free.
// Q is pre-scaled by 1/sqrt(64)*log2(e) so attention works in exp2 domain directly.
// V epilogue: per-wave 64x64 LDS transpose -> coalesced 16B stores along s.
__global__ __launch_bounds__(256) void qkv_gemm_kernel(
    const unsigned short* __restrict__ xb, const unsigned short* __restrict__ wt,
    const float* __restrict__ bias,
    unsigned short* __restrict__ Qb, unsigned short* __restrict__ Kb,
    unsigned short* __restrict__ Vt) {
  __shared__ __align__(16) unsigned char Sh[2][128 * 128];  // As, Bs (contiguous)
  unsigned char* const As = Sh[0];
  unsigned char* const Bs = Sh[1];
  const int t = threadIdx.x;
  const int lane = t & 63;
  const int wave = t >> 6;
  const int wm = (wave >> 1) * 64, wn = (wave & 1) * 64;
  const int lr = lane & 15, g = lane >> 4;
  const int m0 = blockIdx.x * 128, n0 = blockIdx.y * 128;

  f32x4 acc[4][4];
  #pragma unroll
  for (int i = 0; i < 4; ++i)
    #pragma unroll
    for (int j = 0; j < 4; ++j) acc[i][j] = f32x4{0.f, 0.f, 0.f, 0.f};

  for (int k0 = 0; k0 < DM; k0 += 64) {
    __syncthreads();
    #pragma unroll
    for (int i = 0; i < 4; ++i) {
      int c = t + i * 256;            // 1024 chunks of 16B per tile
      int row = c >> 3;               // 0..127
      int cc = (c & 7) ^ (row & 7);   // inverse swizzle on the GLOBAL side
      async_copy16(xb + (size_t)(m0 + row) * DM + k0 + cc * 8, As + c * 16);
      async_copy16(wt + (size_t)(n0 + row) * DM + k0 + cc * 8, Bs + c * 16);
    }
    __syncthreads();  // barrier drains vmcnt -> tiles ready

    bf16x8 af[2][4], bfr[2][4];
    #pragma unroll
    for (int kk = 0; kk < 2; ++kk) {
      #pragma unroll
      for (int i = 0; i < 4; ++i) {
        int ra = wm + i * 16 + lr;
        af[kk][i] = *(const bf16x8*)(As + ((ra * 128 + kk * 64 + g * 16) ^ ((ra & 7) << 4)));
        int rb = wn + i * 16 + lr;
        bfr[kk][i] = *(const bf16x8*)(Bs + ((rb * 128 + kk * 64 + g * 16) ^ ((rb & 7) << 4)));
      }
    }
    #pragma unroll
    for (int kk = 0; kk < 2; ++kk)
      #pragma unroll
      for (int mi = 0; mi < 4; ++mi)
        #pragma unroll
        for (int ni = 0; ni < 4; ++ni)
          acc[mi][ni] = __builtin_amdgcn_mfma_f32_16x16x32_bf16(
              af[kk][mi], bfr[kk][ni], acc[mi][ni], 0, 0, 0);
  }

  __syncthreads();  // all LDS reads of the K-loop done; Sh reusable as scratch

  // wave's 64x64 subtile: rows m0+wm+{0..63}, cols n0+wn+{0..63}
  // a 64-aligned col range lies in exactly one (head, typ): n = 192h + 64typ + d
  const float QSC = 0.18033688011112042f;  // 1/sqrt(64) * log2(e), folded into Q
  const int nbase = n0 + wn;
  const int h = nbase / 192;
  const int typ = (nbase % 192) >> 6;
  const int b = m0 >> 11;                  // whole block in one batch (128 | 2048)
  const int bh = b * NH + h;

  if (typ == 2) {
    // ---- V: LDS transpose (col-major, swizzled) -> coalesced V^T stores ----
    unsigned char* const T = Sh[0] + wave * 8192;  // 64 cols x 64 rows x bf16
    #pragma unroll
    for (int ni = 0; ni < 4; ++ni) {
      int col = ni * 16 + lr;                      // = d
      float bv = bias[nbase + col];
      #pragma unroll
      for (int mi = 0; mi < 4; ++mi) {
        bf16x4 w;                                  // rows mi*16+g*4+{0..3}
        w[0] = (__bf16)(acc[mi][ni][0] + bv);
        w[1] = (__bf16)(acc[mi][ni][1] + bv);
        w[2] = (__bf16)(acc[mi][ni][2] + bv);
        w[3] = (__bf16)(acc[mi][ni][3] + bv);
        int byte = (col * 128 + (mi * 16 + g * 4) * 2) ^ ((col & 7) << 4);
        *(bf16x4*)(T + byte) = w;                  // 8B write, ~conflict-free
      }
    }
    asm volatile("s_waitcnt lgkmcnt(0)" ::: "memory");  // wave-local drain
    __builtin_amdgcn_sched_barrier(0);
    const int s0 = (m0 & 2047) + wm + (lane & 7) * 8;
    #pragma unroll
    for (int i = 0; i < 8; ++i) {
      int col = i * 8 + (lane >> 3);               // d
      int byte = (col * 128 + (lane & 7) * 16) ^ ((col & 7) << 4);
      bf16x8 v = *(const bf16x8*)(T + byte);       // rows s0..s0+7
      *(bf16x8*)(Vt + ((size_t)bh * HD + col) * S_LEN + s0) = v;
    }
  } else {
    // ---- Q/K: direct stores (16 contiguous d per instruction, L2 merges) ----
    unsigned short* const dst = (typ == 0) ? Qb : Kb;
    const float sc = (typ == 0) ? QSC : 1.0f;
    #pragma unroll
    for (int ni = 0; ni < 4; ++ni) {
      int d = ni * 16 + lr;
      float bv = bias[nbase + d];
      #pragma unroll
      for (int mi = 0; mi < 4; ++mi) {
        #pragma unroll
        for (int r = 0; r < 4; ++r) {
          int s = (m0 & 2047) + wm + mi * 16 + g * 4 + r;
          dst[((size_t)bh * S_LEN + s) * HD + d] = f2bf((acc[mi][ni][r] + bv) * sc);
        }
      }
    }
  }
}

// ---------------- flash attention: swapped QK^T, lane-local softmax ----------------
// 4 waves x 16 q rows, KVBLK=64, double-buffered K/V with STATIC buffer indexing.
// S^T = mfma(kf, qf) with C seeded to -m: sacc = S - m straight off the matrix pipe.
// Row-sum of P comes from an extra ones-MFMA (lacc), so softmax has NO cross-lane
// ops and NO adds on the common path; defer-max check is a lane-local __all().
__global__ __launch_bounds__(256) void attn_kernel(
    const unsigned short* __restrict__ Qb, const unsigned short* __restrict__ Kb,
    const unsigned short* __restrict__ Vt, float* __restrict__ out) {
  __shared__ __align__(16) unsigned char Ks[2][64 * 128];   // K tile [64 keys][64 d]
  __shared__ __align__(16) unsigned char Vs[2][64 * 128];   // V^T tile [64 d][64 j]
  __shared__ __align__(16) unsigned char Ps[4][16 * 128];   // per-wave P [16 q][64 j]
  const int t = threadIdx.x;
  const int lane = t & 63;
  const int wave = t >> 6;
  const int lr = lane & 15, g = lane >> 4;
  const int bh = blockIdx.y;
  const int q0 = blockIdx.x * 64 + wave * 16;

  const unsigned short* Qbh = Qb + (size_t)bh * S_LEN * HD;
  const unsigned short* Kbh = Kb + (size_t)bh * S_LEN * HD;
  const unsigned short* Vbh = Vt + (size_t)bh * HD * S_LEN;

  bf16x8 qf[2];  // Q fragment (pre-scaled by 1/8*log2e at GEMM epilogue)
  #pragma unroll
  for (int kk = 0; kk < 2; ++kk)
    qf[kk] = *(const bf16x8*)(Qbh + (size_t)(q0 + lr) * HD + kk * 32 + g * 8);

  // all-ones A-fragment for the row-sum MFMA
  union { unsigned short u[8]; bf16x8 v; } one_c;
  #pragma unroll
  for (int j = 0; j < 8; ++j) one_c.u[j] = 0x3F80;  // bf16 1.0
  const bf16x8 ones8 = one_c.v;

  // ---- loop-invariant swizzled LDS offsets (live in VGPRs across the loop) ----
  int kvOff[4][2];                      // K and V share: row = i*16+lr
  #pragma unroll
  for (int i = 0; i < 4; ++i)
    #pragma unroll
    for (int kk = 0; kk < 2; ++kk) {
      int r = i * 16 + lr;
      kvOff[i][kk] = (r * 128 + kk * 64 + g * 16) ^ ((r & 7) << 4);
    }
  unsigned char* const Pw = Ps[wave];
  int pWr[4];                           // P write: row lr, keys ni*16+4g+{0..3}
  #pragma unroll
  for (int ni = 0; ni < 4; ++ni)
    pWr[ni] = (lr * 128 + ni * 32 + g * 8) ^ ((lr & 7) << 4);
  // P read offsets == kvOff[0][kk] (row = lr)

  // staging: per-lane source offsets (elements) and LDS chunk indices
  int c0 = t, c1 = t + 256;
  int row0 = c0 >> 3, row1 = c1 >> 3;
  int cc0 = (c0 & 7) ^ (row0 & 7), cc1 = (c1 & 7) ^ (row1 & 7);
  const int kGO0 = row0 * HD + cc0 * 8, kGO1 = row1 * HD + cc1 * 8;
  const int vGO0 = row0 * S_LEN + cc0 * 8, vGO1 = row1 * S_LEN + cc1 * 8;

  float m = 0.f;                         // running max (exp2 domain), defer-max
  f32x4 lacc = f32x4{0.f, 0.f, 0.f, 0.f};  // sum(P) per q via ones-MFMA
  f32x4 oacc[4];
  #pragma unroll
  for (int di = 0; di < 4; ++di) oacc[di] = f32x4{0.f, 0.f, 0.f, 0.f};

  auto stage = [&](int kt, int buf) __attribute__((always_inline)) {
    const unsigned short* kp = Kbh + (size_t)kt * (64 * HD);
    const unsigned short* vp = Vbh + kt * 64;
    async_copy16(kp + kGO0, &Ks[buf][c0 * 16]);
    async_copy16(vp + vGO0, &Vs[buf][c0 * 16]);
    async_copy16(kp + kGO1, &Ks[buf][c1 * 16]);
    async_copy16(vp + vGO1, &Vs[buf][c1 * 16]);
  };

  auto compute = [&](int buf) __attribute__((always_inline)) {
    // S^T - m = K·Q^T with C pre-seeded to -m (matrix pipe does the subtraction)
    const float nm = -m;
    f32x4 sacc[4];
    #pragma unroll
    for (int ni = 0; ni < 4; ++ni) sacc[ni] = f32x4{nm, nm, nm, nm};
    __builtin_amdgcn_s_setprio(1);
    #pragma unroll
    for (int ni = 0; ni < 4; ++ni)
      #pragma unroll
      for (int kk = 0; kk < 2; ++kk) {
        bf16x8 kf = *(const bf16x8*)(&Ks[buf][kvOff[ni][kk]]);
        sacc[ni] = __builtin_amdgcn_mfma_f32_16x16x32_bf16(kf, qf[kk], sacc[ni], 0, 0, 0);
      }
    __builtin_amdgcn_s_setprio(0);

    // lane-local max of the 16 (S-m) values, v_max3 tree (8 ops)
    float a0 = fmaxf(fmaxf(sacc[0][0], sacc[0][1]), sacc[0][2]);
    float a1 = fmaxf(fmaxf(sacc[0][3], sacc[1][0]), sacc[1][1]);
    float a2 = fmaxf(fmaxf(sacc[1][2], sacc[1][3]), sacc[2][0]);
    float a3 = fmaxf(fmaxf(sacc[2][1], sacc[2][2]), sacc[2][3]);
    float a4 = fmaxf(fmaxf(sacc[3][0], sacc[3][1]), sacc[3][2]);
    float b0 = fmaxf(fmaxf(a0, a1), a2);
    float b1 = fmaxf(fmaxf(a3, a4), sacc[3][3]);
    float tm = fmaxf(b0, b1);

    if (!__all(tm <= 8.f)) {             // rare: real max growth -> rescale
      float tmr = fmaxf(tm, __shfl_xor(tm, 16));
      tmr = fmaxf(tmr, __shfl_xor(tmr, 32));
      float alpha = exp2f(-tmr);
      m += tmr;
      lacc *= alpha;
      #pragma unroll
      for (int di = 0; di < 4; ++di) oacc[di] *= alpha;
      #pragma unroll
      for (int ni = 0; ni < 4; ++ni)
        #pragma unroll
        for (int r = 0; r < 4; ++r) sacc[ni][r] -= tmr;
    }

    // P = exp2(S - m), bounded by 2^8; straight to bf16 LDS
    #pragma unroll
    for (int ni = 0; ni < 4; ++ni) {
      bf16x4 w;
      w[0] = (__bf16)exp2f(sacc[ni][0]);
      w[1] = (__bf16)exp2f(sacc[ni][1]);
      w[2] = (__bf16)exp2f(sacc[ni][2]);
      w[3] = (__bf16)exp2f(sacc[ni][3]);
      *(bf16x4*)(Pw + pWr[ni]) = w;
    }

    // drain the wave-local P ds_writes before reading them back
    asm volatile("s_waitcnt lgkmcnt(0)" ::: "memory");
    __builtin_amdgcn_sched_barrier(0);

    // O^T += V^T·P^T ; row-sum += ones·P^T (both on the matrix pipe)
    bf16x8 pf[2];
    #pragma unroll
    for (int kk = 0; kk < 2; ++kk)
      pf[kk] = *(const bf16x8*)(Pw + kvOff[0][kk]);
    __builtin_amdgcn_s_setprio(1);
    #pragma unroll
    for (int di = 0; di < 4; ++di)
      #pragma unroll
      for (int kk = 0; kk < 2; ++kk) {
        bf16x8 vf = *(const bf16x8*)(&Vs[buf][kvOff[di][kk]]);
        oacc[di] = __builtin_amdgcn_mfma_f32_16x16x32_bf16(vf, pf[kk], oacc[di], 0, 0, 0);
      }
    #pragma unroll
    for (int kk = 0; kk < 2; ++kk)
      lacc = __builtin_amdgcn_mfma_f32_16x16x32_bf16(ones8, pf[kk], lacc, 0, 0, 0);
    __builtin_amdgcn_s_setprio(0);
  };

  stage(0, 0);
  __syncthreads();  // drains vmcnt -> tile 0 ready

  for (int kt = 0; kt < S_LEN / 64; kt += 2) {
    stage(kt + 1, 1);                    // prefetch overlaps compute (kt+1 <= 31)
    compute(0);
    __syncthreads();                     // buf1 landed; buf0 reads done
    if (kt + 2 < S_LEN / 64) stage(kt + 2, 0);
    compute(1);
    __syncthreads();                     // buf0 landed; buf1 reads done
  }

  // normalize + write: oacc[di][r] = O[q=lr][d = di*16 + 4g + r]; lacc[*] = sum P
  float inv = 1.0f / lacc[0];
  float* outp = out + ((size_t)bh * S_LEN + q0 + lr) * HD;
  #pragma unroll
  for (int di = 0; di < 4; ++di) {
    f32x4 o = oacc[di] * inv;
    *(f32x4*)(outp + di * 16 + g * 4) = o;
  }
}

extern "C" void kernel_launch(void* const* d_in, const int* in_sizes, int n_in,
                              void* d_out, int out_size, void* d_ws, size_t ws_size,
                              hipStream_t stream) {
  const float* x    = (const float*)d_in[0];
  const float* W    = (const float*)d_in[1];
  const float* bias = (const float*)d_in[2];
  float* out = (float*)d_out;

  // workspace partition (bf16 everywhere): ~38 MB total
  unsigned short* xb = (unsigned short*)d_ws;
  unsigned short* wt = xb + (size_t)MROWS * DM;
  unsigned short* Qb = wt + (size_t)NQKV * DM;
  unsigned short* Kb = Qb + (size_t)NBH * S_LEN * HD;
  unsigned short* Vt = Kb + (size_t)NBH * S_LEN * HD;

  cast_x_kernel<<<(MROWS * DM) / (256 * 8), 256, 0, stream>>>(x, xb);
  transpose_w_kernel<<<dim3(NQKV / 32, DM / 32), dim3(32, 8), 0, stream>>>(W, wt);
  qkv_gemm_kernel<<<dim3(MROWS / 128, NQKV / 128), 256, 0, stream>>>(xb, wt, bias, Qb, Kb, Vt);
  attn_kernel<<<dim3(S_LEN / 64, NBH), 256, 0, stream>>>(Qb, Kb, Vt, out);
}

// Round 7
// 115.102 us; speedup vs baseline: 1.5957x; 1.1238x over previous
//
#include <hip/hip_runtime.h>
#include <stdint.h>
#include <stddef.h>

#define S_LEN 2048
#define NH 16
#define HD 64          // head dim
#define DM 1024        // model dim
#define NQKV 3072      // 3*DM
#define MROWS 4096     // B*S
#define NBH 32         // B*NH

typedef float f32x4 __attribute__((ext_vector_type(4)));
typedef __bf16 bf16x8 __attribute__((ext_vector_type(8)));
typedef __bf16 bf16x4 __attribute__((ext_vector_type(4)));
typedef short short8_t __attribute__((ext_vector_type(8)));

// round-to-nearest-even fp32 -> bf16 (inputs finite)
__device__ __forceinline__ unsigned short f2bf(float f) {
  union { float f; unsigned int u; } v; v.f = f;
  unsigned int u = v.u;
  u += 0x7FFFu + ((u >> 16) & 1u);
  return (unsigned short)(u >> 16);
}

// async global->LDS, 16B per lane. LDS dest must be (wave-uniform base + lane*16).
__device__ __forceinline__ void async_copy16(const void* g, void* l) {
  __builtin_amdgcn_global_load_lds(
      (const __attribute__((address_space(1))) void*)g,
      (__attribute__((address_space(3))) void*)l, 16, 0, 0);
}

// ---------------- precast x -> bf16 ----------------
__global__ __launch_bounds__(256) void cast_x_kernel(const float* __restrict__ x,
                                                     unsigned short* __restrict__ xb) {
  size_t i = ((size_t)blockIdx.x * 256 + threadIdx.x) * 8;
  f32x4 a = *(const f32x4*)(x + i);
  f32x4 b = *(const f32x4*)(x + i + 4);
  union { unsigned short u[8]; short8_t v; } o;
  o.u[0] = f2bf(a[0]); o.u[1] = f2bf(a[1]); o.u[2] = f2bf(a[2]); o.u[3] = f2bf(a[3]);
  o.u[4] = f2bf(b[0]); o.u[5] = f2bf(b[1]); o.u[6] = f2bf(b[2]); o.u[7] = f2bf(b[3]);
  *(short8_t*)(xb + i) = o.v;
}

// ---------------- W[K][N] -> Wt[N][K] bf16 (LDS tile transpose) ----------------
__global__ __launch_bounds__(256) void transpose_w_kernel(const float* __restrict__ W,
                                                          unsigned short* __restrict__ wt) {
  __shared__ float tile[32][33];
  const int n0 = blockIdx.x * 32;
  const int k0 = blockIdx.y * 32;
  const int tx = threadIdx.x;   // 0..31
  const int ty = threadIdx.y;   // 0..7
  #pragma unroll
  for (int i = 0; i < 4; ++i)
    tile[ty + i * 8][tx] = W[(size_t)(k0 + ty + i * 8) * NQKV + n0 + tx];
  __syncthreads();
  #pragma unroll
  for (int i = 0; i < 4; ++i)
    wt[(size_t)(n0 + ty + i * 8) * DM + k0 + tx] = f2bf(tile[tx][ty + i * 8]);
}

// ---------------- QKV GEMM: [4096,1024] x [1024,3072] + bias -> Q,K,V^T (bf16) ----------------
// 128x128 tile, BK=64, 4 waves (2x2), 16x16x32 bf16 MFMA, global_load_lds staging
// with pre-swizzled source so LDS reads (^((row&7)<<4)) are bank-conflict-free.
// Q is pre-scaled by 1/sqrt(64)*log2(e) so attention works in exp2 domain directly.
// V epilogue: per-wave 64x64 LDS transpose -> coalesced 16B stores along s.
__global__ __launch_bounds__(256) void qkv_gemm_kernel(
    const unsigned short* __restrict__ xb, const unsigned short* __restrict__ wt,
    const float* __restrict__ bias,
    unsigned short* __restrict__ Qb, unsigned short* __restrict__ Kb,
    unsigned short* __restrict__ Vt) {
  __shared__ __align__(16) unsigned char Sh[2][128 * 128];  // As, Bs (contiguous)
  unsigned char* const As = Sh[0];
  unsigned char* const Bs = Sh[1];
  const int t = threadIdx.x;
  const int lane = t & 63;
  const int wave = t >> 6;
  const int wm = (wave >> 1) * 64, wn = (wave & 1) * 64;
  const int lr = lane & 15, g = lane >> 4;
  const int m0 = blockIdx.x * 128, n0 = blockIdx.y * 128;

  f32x4 acc[4][4];
  #pragma unroll
  for (int i = 0; i < 4; ++i)
    #pragma unroll
    for (int j = 0; j < 4; ++j) acc[i][j] = f32x4{0.f, 0.f, 0.f, 0.f};

  for (int k0 = 0; k0 < DM; k0 += 64) {
    __syncthreads();
    #pragma unroll
    for (int i = 0; i < 4; ++i) {
      int c = t + i * 256;            // 1024 chunks of 16B per tile
      int row = c >> 3;               // 0..127
      int cc = (c & 7) ^ (row & 7);   // inverse swizzle on the GLOBAL side
      async_copy16(xb + (size_t)(m0 + row) * DM + k0 + cc * 8, As + c * 16);
      async_copy16(wt + (size_t)(n0 + row) * DM + k0 + cc * 8, Bs + c * 16);
    }
    __syncthreads();  // barrier drains vmcnt -> tiles ready

    bf16x8 af[2][4], bfr[2][4];
    #pragma unroll
    for (int kk = 0; kk < 2; ++kk) {
      #pragma unroll
      for (int i = 0; i < 4; ++i) {
        int ra = wm + i * 16 + lr;
        af[kk][i] = *(const bf16x8*)(As + ((ra * 128 + kk * 64 + g * 16) ^ ((ra & 7) << 4)));
        int rb = wn + i * 16 + lr;
        bfr[kk][i] = *(const bf16x8*)(Bs + ((rb * 128 + kk * 64 + g * 16) ^ ((rb & 7) << 4)));
      }
    }
    #pragma unroll
    for (int kk = 0; kk < 2; ++kk)
      #pragma unroll
      for (int mi = 0; mi < 4; ++mi)
        #pragma unroll
        for (int ni = 0; ni < 4; ++ni)
          acc[mi][ni] = __builtin_amdgcn_mfma_f32_16x16x32_bf16(
              af[kk][mi], bfr[kk][ni], acc[mi][ni], 0, 0, 0);
  }

  __syncthreads();  // all LDS reads of the K-loop done; Sh reusable as scratch

  // wave's 64x64 subtile: rows m0+wm+{0..63}, cols n0+wn+{0..63}
  // a 64-aligned col range lies in exactly one (head, typ): n = 192h + 64typ + d
  const float QSC = 0.18033688011112042f;  // 1/sqrt(64) * log2(e), folded into Q
  const int nbase = n0 + wn;
  const int h = nbase / 192;
  const int typ = (nbase % 192) >> 6;
  const int b = m0 >> 11;                  // whole block in one batch (128 | 2048)
  const int bh = b * NH + h;

  if (typ == 2) {
    // ---- V: LDS transpose (col-major, swizzled) -> coalesced V^T stores ----
    unsigned char* const T = Sh[0] + wave * 8192;  // 64 cols x 64 rows x bf16
    #pragma unroll
    for (int ni = 0; ni < 4; ++ni) {
      int col = ni * 16 + lr;                      // = d
      float bv = bias[nbase + col];
      #pragma unroll
      for (int mi = 0; mi < 4; ++mi) {
        bf16x4 w;                                  // rows mi*16+g*4+{0..3}
        w[0] = (__bf16)(acc[mi][ni][0] + bv);
        w[1] = (__bf16)(acc[mi][ni][1] + bv);
        w[2] = (__bf16)(acc[mi][ni][2] + bv);
        w[3] = (__bf16)(acc[mi][ni][3] + bv);
        int byte = (col * 128 + (mi * 16 + g * 4) * 2) ^ ((col & 7) << 4);
        *(bf16x4*)(T + byte) = w;                  // 8B write, ~conflict-free
      }
    }
    asm volatile("s_waitcnt lgkmcnt(0)" ::: "memory");  // wave-local drain
    __builtin_amdgcn_sched_barrier(0);
    const int s0 = (m0 & 2047) + wm + (lane & 7) * 8;
    #pragma unroll
    for (int i = 0; i < 8; ++i) {
      int col = i * 8 + (lane >> 3);               // d
      int byte = (col * 128 + (lane & 7) * 16) ^ ((col & 7) << 4);
      bf16x8 v = *(const bf16x8*)(T + byte);       // rows s0..s0+7
      *(bf16x8*)(Vt + ((size_t)bh * HD + col) * S_LEN + s0) = v;
    }
  } else {
    // ---- Q/K: direct stores (16 contiguous d per instruction, L2 merges) ----
    unsigned short* const dst = (typ == 0) ? Qb : Kb;
    const float sc = (typ == 0) ? QSC : 1.0f;
    #pragma unroll
    for (int ni = 0; ni < 4; ++ni) {
      int d = ni * 16 + lr;
      float bv = bias[nbase + d];
      #pragma unroll
      for (int mi = 0; mi < 4; ++mi) {
        #pragma unroll
        for (int r = 0; r < 4; ++r) {
          int s = (m0 & 2047) + wm + mi * 16 + g * 4 + r;
          dst[((size_t)bh * S_LEN + s) * HD + d] = f2bf((acc[mi][ni][r] + bv) * sc);
        }
      }
    }
  }
}

// ---------------- flash attention: swapped QK^T, lane-local softmax ----------------
// 8 waves x 16 q rows (128 q/block): same per-wave structure as the verified r4
// kernel, but each staged K/V tile now serves 2x the q rows and 2 blocks/CU give
// ~2x the resident waves for latency hiding. P write->read ordering is left to
// the compiler (plain LDS accesses to the same array), so independent Vs reads
// can be hoisted into the P-drain bubble.
__global__ __launch_bounds__(512) void attn_kernel(
    const unsigned short* __restrict__ Qb, const unsigned short* __restrict__ Kb,
    const unsigned short* __restrict__ Vt, float* __restrict__ out) {
  __shared__ __align__(16) unsigned char Ks[2][64 * 128];   // K tile [64 keys][64 d]
  __shared__ __align__(16) unsigned char Vs[2][64 * 128];   // V^T tile [64 d][64 j]
  __shared__ __align__(16) unsigned char Ps[8][16 * 128];   // per-wave P [16 q][64 j]
  const int t = threadIdx.x;
  const int lane = t & 63;
  const int wave = t >> 6;                // 0..7
  const int lr = lane & 15, g = lane >> 4;
  const int bh = blockIdx.y;
  const int q0 = blockIdx.x * 128 + wave * 16;

  const unsigned short* Qbh = Qb + (size_t)bh * S_LEN * HD;
  const unsigned short* Kbh = Kb + (size_t)bh * S_LEN * HD;
  const unsigned short* Vbh = Vt + (size_t)bh * HD * S_LEN;

  bf16x8 qf[2];  // Q fragment (pre-scaled by 1/8*log2e at GEMM epilogue)
  #pragma unroll
  for (int kk = 0; kk < 2; ++kk)
    qf[kk] = *(const bf16x8*)(Qbh + (size_t)(q0 + lr) * HD + kk * 32 + g * 8);

  // all-ones A-fragment for the row-sum MFMA
  union { unsigned short u[8]; bf16x8 v; } one_c;
  #pragma unroll
  for (int j = 0; j < 8; ++j) one_c.u[j] = 0x3F80;  // bf16 1.0
  const bf16x8 ones8 = one_c.v;

  // ---- loop-invariant swizzled LDS offsets (live in VGPRs across the loop) ----
  int kvOff[4][2];                      // K and V share: row = i*16+lr
  #pragma unroll
  for (int i = 0; i < 4; ++i)
    #pragma unroll
    for (int kk = 0; kk < 2; ++kk) {
      int r = i * 16 + lr;
      kvOff[i][kk] = (r * 128 + kk * 64 + g * 16) ^ ((r & 7) << 4);
    }
  unsigned char* const Pw = Ps[wave];
  int pWr[4];                           // P write: row lr, keys ni*16+4g+{0..3}
  #pragma unroll
  for (int ni = 0; ni < 4; ++ni)
    pWr[ni] = (lr * 128 + ni * 32 + g * 8) ^ ((lr & 7) << 4);
  // P read offsets == kvOff[0][kk] (row = lr)

  // staging: 512 threads, one 16B chunk per thread per buffer
  const int c0 = t;                     // 0..511
  const int row0 = c0 >> 3;             // 0..63
  const int cc0 = (c0 & 7) ^ (row0 & 7);
  const int kGO0 = row0 * HD + cc0 * 8;
  const int vGO0 = row0 * S_LEN + cc0 * 8;

  float m = 0.f;                         // running max (exp2 domain), defer-max
  f32x4 lacc = f32x4{0.f, 0.f, 0.f, 0.f};  // sum(P) per q via ones-MFMA
  f32x4 oacc[4];
  #pragma unroll
  for (int di = 0; di < 4; ++di) oacc[di] = f32x4{0.f, 0.f, 0.f, 0.f};

  auto stage = [&](int kt, int buf) __attribute__((always_inline)) {
    const unsigned short* kp = Kbh + (size_t)kt * (64 * HD);
    const unsigned short* vp = Vbh + kt * 64;
    async_copy16(kp + kGO0, &Ks[buf][c0 * 16]);
    async_copy16(vp + vGO0, &Vs[buf][c0 * 16]);
  };

  auto compute = [&](int buf) __attribute__((always_inline)) {
    // S^T - m = K·Q^T with C pre-seeded to -m (matrix pipe does the subtraction)
    const float nm = -m;
    f32x4 sacc[4];
    #pragma unroll
    for (int ni = 0; ni < 4; ++ni) sacc[ni] = f32x4{nm, nm, nm, nm};
    __builtin_amdgcn_s_setprio(1);
    #pragma unroll
    for (int ni = 0; ni < 4; ++ni)
      #pragma unroll
      for (int kk = 0; kk < 2; ++kk) {
        bf16x8 kf = *(const bf16x8*)(&Ks[buf][kvOff[ni][kk]]);
        sacc[ni] = __builtin_amdgcn_mfma_f32_16x16x32_bf16(kf, qf[kk], sacc[ni], 0, 0, 0);
      }
    __builtin_amdgcn_s_setprio(0);

    // lane-local max of the 16 (S-m) values, v_max3 tree (8 ops)
    float a0 = fmaxf(fmaxf(sacc[0][0], sacc[0][1]), sacc[0][2]);
    float a1 = fmaxf(fmaxf(sacc[0][3], sacc[1][0]), sacc[1][1]);
    float a2 = fmaxf(fmaxf(sacc[1][2], sacc[1][3]), sacc[2][0]);
    float a3 = fmaxf(fmaxf(sacc[2][1], sacc[2][2]), sacc[2][3]);
    float a4 = fmaxf(fmaxf(sacc[3][0], sacc[3][1]), sacc[3][2]);
    float b0 = fmaxf(fmaxf(a0, a1), a2);
    float b1 = fmaxf(fmaxf(a3, a4), sacc[3][3]);
    float tm = fmaxf(b0, b1);

    if (!__all(tm <= 8.f)) {             // rare: real max growth -> rescale
      float tmr = fmaxf(tm, __shfl_xor(tm, 16));
      tmr = fmaxf(tmr, __shfl_xor(tmr, 32));
      float alpha = exp2f(-tmr);
      m += tmr;
      lacc *= alpha;
      #pragma unroll
      for (int di = 0; di < 4; ++di) oacc[di] *= alpha;
      #pragma unroll
      for (int ni = 0; ni < 4; ++ni)
        #pragma unroll
        for (int r = 0; r < 4; ++r) sacc[ni][r] -= tmr;
    }

    // P = exp2(S - m), bounded by 2^8; straight to bf16 LDS
    #pragma unroll
    for (int ni = 0; ni < 4; ++ni) {
      bf16x4 w;
      w[0] = (__bf16)exp2f(sacc[ni][0]);
      w[1] = (__bf16)exp2f(sacc[ni][1]);
      w[2] = (__bf16)exp2f(sacc[ni][2]);
      w[3] = (__bf16)exp2f(sacc[ni][3]);
      *(bf16x4*)(Pw + pWr[ni]) = w;
    }
    // (compiler inserts the minimal lgkmcnt for the P write->read RAW below;
    //  independent Vs reads are free to schedule into that bubble)

    // O^T += V^T·P^T ; row-sum += ones·P^T (both on the matrix pipe)
    bf16x8 pf[2];
    #pragma unroll
    for (int kk = 0; kk < 2; ++kk)
      pf[kk] = *(const bf16x8*)(Pw + kvOff[0][kk]);
    __builtin_amdgcn_s_setprio(1);
    #pragma unroll
    for (int di = 0; di < 4; ++di)
      #pragma unroll
      for (int kk = 0; kk < 2; ++kk) {
        bf16x8 vf = *(const bf16x8*)(&Vs[buf][kvOff[di][kk]]);
        oacc[di] = __builtin_amdgcn_mfma_f32_16x16x32_bf16(vf, pf[kk], oacc[di], 0, 0, 0);
      }
    #pragma unroll
    for (int kk = 0; kk < 2; ++kk)
      lacc = __builtin_amdgcn_mfma_f32_16x16x32_bf16(ones8, pf[kk], lacc, 0, 0, 0);
    __builtin_amdgcn_s_setprio(0);
  };

  stage(0, 0);
  __syncthreads();  // drains vmcnt -> tile 0 ready

  for (int kt = 0; kt < S_LEN / 64; kt += 2) {
    stage(kt + 1, 1);                    // prefetch overlaps compute (kt+1 <= 31)
    compute(0);
    __syncthreads();                     // buf1 landed; buf0 reads done
    if (kt + 2 < S_LEN / 64) stage(kt + 2, 0);
    compute(1);
    __syncthreads();                     // buf0 landed; buf1 reads done
  }

  // normalize + write: oacc[di][r] = O[q=lr][d = di*16 + 4g + r]; lacc[*] = sum P
  float inv = 1.0f / lacc[0];
  float* outp = out + ((size_t)bh * S_LEN + q0 + lr) * HD;
  #pragma unroll
  for (int di = 0; di < 4; ++di) {
    f32x4 o = oacc[di] * inv;
    *(f32x4*)(outp + di * 16 + g * 4) = o;
  }
}

extern "C" void kernel_launch(void* const* d_in, const int* in_sizes, int n_in,
                              void* d_out, int out_size, void* d_ws, size_t ws_size,
                              hipStream_t stream) {
  const float* x    = (const float*)d_in[0];
  const float* W    = (const float*)d_in[1];
  const float* bias = (const float*)d_in[2];
  float* out = (float*)d_out;

  // workspace partition (bf16 everywhere): ~38 MB total
  unsigned short* xb = (unsigned short*)d_ws;
  unsigned short* wt = xb + (size_t)MROWS * DM;
  unsigned short* Qb = wt + (size_t)NQKV * DM;
  unsigned short* Kb = Qb + (size_t)NBH * S_LEN * HD;
  unsigned short* Vt = Kb + (size_t)NBH * S_LEN * HD;

  cast_x_kernel<<<(MROWS * DM) / (256 * 8), 256, 0, stream>>>(x, xb);
  transpose_w_kernel<<<dim3(NQKV / 32, DM / 32), dim3(32, 8), 0, stream>>>(W, wt);
  qkv_gemm_kernel<<<dim3(MROWS / 128, NQKV / 128), 256, 0, stream>>>(xb, wt, bias, Qb, Kb, Vt);
  attn_kernel<<<dim3(S_LEN / 128, NBH), 512, 0, stream>>>(Qb, Kb, Vt, out);
}